// Round 12
// baseline (96.693 us; speedup 1.0000x reference)
//
#include <hip/hip_runtime.h>
#include <hip/hip_fp16.h>
#include <math.h>

#define EMB_DIM 500
#define TWO_D 1000
#define D4 125                 // float4 groups per half-row (500/4)
#define ROW_F4 250             // float4 per entity row (1000/4)
#define NUM_ENTITIES 14541
#define B_SIZE 16
#define GAMMA_F 12.0f
// PI / ((GAMMA + 2) / EMB_DIM) = pi / 0.028
#define PHASE_SCALE 112.19973762820692f
#define ROT_HALFS (B_SIZE * D4 * 8)    // 16000 halfs = 32000 B (full table)
#define BLK_HALFS (8 * D4 * 8)         // 8000 halfs = 16000 B (one b-group)

// ---------------------------------------------------------------------------
// Kernel 1: precompute rotated head embeddings as fp16, interleaved layout
// rot[b][d4][0..3] = re(4*d4 .. 4*d4+3), rot[b][d4][4..7] = im(...)
// b-major layout => a b-group of 8 is a contiguous 16 KB half of the table.
// ---------------------------------------------------------------------------
__global__ __launch_bounds__(256) void rot_precompute(
    const int* __restrict__ all_h, const int* __restrict__ all_r,
    const float* __restrict__ eemb, const float* __restrict__ remb,
    __half* __restrict__ rot)
{
    int i = blockIdx.x * 256 + threadIdx.x;
    if (i >= B_SIZE * EMB_DIM) return;
    int b = i / EMB_DIM;
    int d = i - b * EMB_DIM;
    int h = all_h[b];
    int r = all_r[b];
    float re_h = eemb[h * TWO_D + d];
    float im_h = eemb[h * TWO_D + EMB_DIM + d];
    float ph = remb[r * EMB_DIM + d] * PHASE_SCALE;
    float s, c;
    sincosf(ph, &s, &c);
    int base = ((b * D4 + (d >> 2)) << 3) + (d & 3);
    rot[base]     = __float2half(re_h * c - im_h * s);  // re_rot
    rot[base + 4] = __float2half(re_h * s + im_h * c);  // im_rot
}

// ---------------------------------------------------------------------------
// Kernel 2: B-SPLIT. Block = 16 entities x 8 queries (bg = blockIdx&1).
// Wave = 4 ents x 8 b = 32 accs/lane (vs R9's 64) but SAME 16-evals-per-
// ds_read amortization (the measured driver: R9 16/read=39us, R11 8/read=
// 70us, same inst count). Grid doubles to 1818 (block supply was 3.55/CU,
// residency-starved); LDS halves to 16KB (10 blocks/CU cap); VGPR ~100
// (4 waves/SIMD cap). Cost: entity table streamed 2x (L3-absorbed).
// ---------------------------------------------------------------------------
__global__ __launch_bounds__(256) void rotate_score(
    const float* __restrict__ eemb,
    const __half* __restrict__ rot,      // nullptr -> compute in-kernel
    const int* __restrict__ all_h, const int* __restrict__ all_r,
    const float* __restrict__ remb,
    float* __restrict__ out)
{
    __shared__ __half lrot[BLK_HALFS];   // 16000 bytes

    const int tid = threadIdx.x;
    const int bg  = blockIdx.x & 1;      // b-group: queries bg*8 .. bg*8+7

    if (rot != nullptr) {
        const float4* src = (const float4*)rot + bg * (BLK_HALFS / 8);
        float4* dst = (float4*)lrot;
        for (int i = tid; i < BLK_HALFS / 8; i += 256) dst[i] = src[i];
    } else {
        for (int i = tid; i < 8 * EMB_DIM; i += 256) {
            int b8 = i / EMB_DIM;
            int d = i - b8 * EMB_DIM;
            int b = bg * 8 + b8;
            int h = all_h[b];
            int r = all_r[b];
            float re_h = eemb[h * TWO_D + d];
            float im_h = eemb[h * TWO_D + EMB_DIM + d];
            float ph = remb[r * EMB_DIM + d] * PHASE_SCALE;
            float s, c;
            sincosf(ph, &s, &c);
            int base = ((b8 * D4 + (d >> 2)) << 3) + (d & 3);
            lrot[base]     = __float2half(re_h * c - im_h * s);
            lrot[base + 4] = __float2half(re_h * s + im_h * c);
        }
    }
    __syncthreads();

    const int lane = tid & 63;
    const int wave = tid >> 6;
    const int e0 = (blockIdx.x >> 1) * 16 + wave * 4;

    int e[4];
#pragma unroll
    for (int k = 0; k < 4; ++k) {
        int ek = e0 + k;
        e[k] = (ek < NUM_ENTITIES) ? ek : (NUM_ENTITIES - 1);
    }

    float v[32];                         // acc[k][b8]: idx = k*8+b8
#pragma unroll
    for (int i = 0; i < 32; ++i) v[i] = 0.0f;

    const float4* lrot4 = (const float4*)lrot;
    const float4* ee4 = (const float4*)eemb;

#pragma unroll
    for (int it = 0; it < 2; ++it) {
        const int d4 = it * 64 + lane;
        if (d4 < D4) {
            float4 tre[4], tim[4];
#pragma unroll
            for (int k = 0; k < 4; ++k) {
                int rb = e[k] * ROW_F4;
                tre[k] = ee4[rb + d4];
                tim[k] = ee4[rb + D4 + d4];
            }
#pragma unroll
            for (int b8 = 0; b8 < 8; ++b8) {
                float4 rv = lrot4[b8 * D4 + d4];
                __half2 p0 = __builtin_bit_cast(__half2, rv.x);
                __half2 p1 = __builtin_bit_cast(__half2, rv.y);
                __half2 p2 = __builtin_bit_cast(__half2, rv.z);
                __half2 p3 = __builtin_bit_cast(__half2, rv.w);
                float rre0 = __low2float(p0), rre1 = __high2float(p0);
                float rre2 = __low2float(p1), rre3 = __high2float(p1);
                float rim0 = __low2float(p2), rim1 = __high2float(p2);
                float rim2 = __low2float(p3), rim3 = __high2float(p3);
#pragma unroll
                for (int k = 0; k < 4; ++k) {
                    float dre, dim;
                    dre = rre0 - tre[k].x; dim = rim0 - tim[k].x;
                    v[k * 8 + b8] += __builtin_amdgcn_sqrtf(dre * dre + dim * dim);
                    dre = rre1 - tre[k].y; dim = rim1 - tim[k].y;
                    v[k * 8 + b8] += __builtin_amdgcn_sqrtf(dre * dre + dim * dim);
                    dre = rre2 - tre[k].z; dim = rim2 - tim[k].z;
                    v[k * 8 + b8] += __builtin_amdgcn_sqrtf(dre * dre + dim * dim);
                    dre = rre3 - tre[k].w; dim = rim3 - tim[k].w;
                    v[k * 8 + b8] += __builtin_amdgcn_sqrtf(dre * dre + dim * dim);
                }
            }
        }
    }

    // Fold lane^32, then 5-stage halving butterfly: lane L in [0,32) ends
    // holding the full 64-lane sum of v[L] (k = L>>3, b8 = L&7).
#pragma unroll
    for (int i = 0; i < 32; ++i) v[i] += __shfl_xor(v[i], 32, 64);
#pragma unroll
    for (int m = 16; m >= 1; m >>= 1) {
        const bool hi = (lane & m) != 0;
#pragma unroll
        for (int i = 0; i < m; ++i) {
            float give = hi ? v[i] : v[m + i];
            float keep = hi ? v[m + i] : v[i];
            v[i] = keep + __shfl_xor(give, m, 64);
        }
    }

    if (lane < 32) {
        const int kk = lane >> 3;        // 0..3
        const int bb = bg * 8 + (lane & 7);
        const int ee = e0 + kk;
        if (ee < NUM_ENTITIES) out[bb * NUM_ENTITIES + ee] = GAMMA_F - v[0];
    }
}

// ---------------------------------------------------------------------------
// Fallback (ws-starved): R9's proven kernel, rot computed in-kernel.
// ---------------------------------------------------------------------------
__global__ __launch_bounds__(256) void rotate_score_fb(
    const float* __restrict__ eemb,
    const int* __restrict__ all_h, const int* __restrict__ all_r,
    const float* __restrict__ remb,
    float* __restrict__ out)
{
    __shared__ __half lrot[ROT_HALFS];
    const int tid = threadIdx.x;
    for (int i = tid; i < B_SIZE * EMB_DIM; i += 256) {
        int b = i / EMB_DIM;
        int d = i - b * EMB_DIM;
        int h = all_h[b];
        int r = all_r[b];
        float re_h = eemb[h * TWO_D + d];
        float im_h = eemb[h * TWO_D + EMB_DIM + d];
        float ph = remb[r * EMB_DIM + d] * PHASE_SCALE;
        float s, c;
        sincosf(ph, &s, &c);
        int base = ((b * D4 + (d >> 2)) << 3) + (d & 3);
        lrot[base]     = __float2half(re_h * c - im_h * s);
        lrot[base + 4] = __float2half(re_h * s + im_h * c);
    }
    __syncthreads();

    const int lane = tid & 63;
    const int wave = tid >> 6;
    const int e0 = blockIdx.x * 16 + wave * 4;
    int e[4];
#pragma unroll
    for (int k = 0; k < 4; ++k) {
        int ek = e0 + k;
        e[k] = (ek < NUM_ENTITIES) ? ek : (NUM_ENTITIES - 1);
    }
    float v[64];
#pragma unroll
    for (int i = 0; i < 64; ++i) v[i] = 0.0f;
    const float4* lrot4 = (const float4*)lrot;
    const float4* ee4 = (const float4*)eemb;
#pragma unroll
    for (int it = 0; it < 2; ++it) {
        const int d4 = it * 64 + lane;
        if (d4 < D4) {
            float4 tre[4], tim[4];
#pragma unroll
            for (int k = 0; k < 4; ++k) {
                int rb = e[k] * ROW_F4;
                tre[k] = ee4[rb + d4];
                tim[k] = ee4[rb + D4 + d4];
            }
#pragma unroll
            for (int b = 0; b < 16; ++b) {
                float4 rvb = lrot4[b * D4 + d4];
                __half2 p0 = __builtin_bit_cast(__half2, rvb.x);
                __half2 p1 = __builtin_bit_cast(__half2, rvb.y);
                __half2 p2 = __builtin_bit_cast(__half2, rvb.z);
                __half2 p3 = __builtin_bit_cast(__half2, rvb.w);
                float rre0 = __low2float(p0), rre1 = __high2float(p0);
                float rre2 = __low2float(p1), rre3 = __high2float(p1);
                float rim0 = __low2float(p2), rim1 = __high2float(p2);
                float rim2 = __low2float(p3), rim3 = __high2float(p3);
#pragma unroll
                for (int k = 0; k < 4; ++k) {
                    float dre, dim;
                    dre = rre0 - tre[k].x; dim = rim0 - tim[k].x;
                    v[k * 16 + b] += __builtin_amdgcn_sqrtf(dre * dre + dim * dim);
                    dre = rre1 - tre[k].y; dim = rim1 - tim[k].y;
                    v[k * 16 + b] += __builtin_amdgcn_sqrtf(dre * dre + dim * dim);
                    dre = rre2 - tre[k].z; dim = rim2 - tim[k].z;
                    v[k * 16 + b] += __builtin_amdgcn_sqrtf(dre * dre + dim * dim);
                    dre = rre3 - tre[k].w; dim = rim3 - tim[k].w;
                    v[k * 16 + b] += __builtin_amdgcn_sqrtf(dre * dre + dim * dim);
                }
            }
        }
    }
#pragma unroll
    for (int m = 32; m >= 1; m >>= 1) {
        const bool hi = (lane & m) != 0;
#pragma unroll
        for (int i = 0; i < m; ++i) {
            float give = hi ? v[i] : v[m + i];
            float keep = hi ? v[m + i] : v[i];
            v[i] = keep + __shfl_xor(give, m, 64);
        }
    }
    const int kk = lane >> 4;
    const int bb = lane & 15;
    const int ee = e0 + kk;
    if (ee < NUM_ENTITIES) out[bb * NUM_ENTITIES + ee] = GAMMA_F - v[0];
}

extern "C" void kernel_launch(void* const* d_in, const int* in_sizes, int n_in,
                              void* d_out, int out_size, void* d_ws, size_t ws_size,
                              hipStream_t stream) {
    const int*   all_h = (const int*)d_in[0];
    const int*   all_r = (const int*)d_in[1];
    const float* eemb  = (const float*)d_in[2];
    const float* remb  = (const float*)d_in[3];
    float* out = (float*)d_out;

    const size_t rot_bytes = (size_t)ROT_HALFS * sizeof(__half);
    if (ws_size >= rot_bytes) {
        __half* rot = (__half*)d_ws;
        rot_precompute<<<(B_SIZE * EMB_DIM + 255) / 256, 256, 0, stream>>>(
            all_h, all_r, eemb, remb, rot);
        int etiles = (NUM_ENTITIES + 15) / 16;   // 909
        rotate_score<<<etiles * 2, 256, 0, stream>>>(
            eemb, rot, all_h, all_r, remb, out);
    } else {
        int nblocks = (NUM_ENTITIES + 15) / 16;  // 909
        rotate_score_fb<<<nblocks, 256, 0, stream>>>(
            eemb, all_h, all_r, remb, out);
    }
}

// Round 13
// 41.848 us; speedup vs baseline: 2.3106x; 2.3106x over previous
//
#include <hip/hip_runtime.h>
#include <hip/hip_fp16.h>
#include <math.h>

#define EMB_DIM 500
#define TWO_D 1000
#define D4 125                 // float4 groups per half-row (500/4)
#define ROW_F4 250             // float4 per entity row (1000/4)
#define NUM_ENTITIES 14541
#define B_SIZE 16
#define GAMMA_F 12.0f
// PI / ((GAMMA + 2) / EMB_DIM) = pi / 0.028
#define PHASE_SCALE 112.19973762820692f
#define ROT_HALFS (B_SIZE * D4 * 8)   // 16000 halfs = 32000 B

// ---------------------------------------------------------------------------
// Kernel 1: precompute rotated head embeddings as fp16, interleaved layout
// rot[b][d4][0..3] = re(4*d4 .. 4*d4+3), rot[b][d4][4..7] = im(...)
// ---------------------------------------------------------------------------
__global__ __launch_bounds__(256) void rot_precompute(
    const int* __restrict__ all_h, const int* __restrict__ all_r,
    const float* __restrict__ eemb, const float* __restrict__ remb,
    __half* __restrict__ rot)
{
    int i = blockIdx.x * 256 + threadIdx.x;
    if (i >= B_SIZE * EMB_DIM) return;
    int b = i / EMB_DIM;
    int d = i - b * EMB_DIM;
    int h = all_h[b];
    int r = all_r[b];
    float re_h = eemb[h * TWO_D + d];
    float im_h = eemb[h * TWO_D + EMB_DIM + d];
    float ph = remb[r * EMB_DIM + d] * PHASE_SCALE;
    float s, c;
    sincosf(ph, &s, &c);
    int base = ((b * D4 + (d >> 2)) << 3) + (d & 3);
    rot[base]     = __float2half(re_h * c - im_h * s);  // re_rot
    rot[base + 4] = __float2half(re_h * s + im_h * c);  // im_rot
}

// ---------------------------------------------------------------------------
// Kernel 2: R9's winning shape (909 blocks, 4 ents/wave, v[64], 16 evals per
// ds_read) + EXPLICIT SOFTWARE PIPELINING:
//  - rot ds_read for b+1 issued before computing b (rc/rn rotation)
//  - all 16 entity float4 loads (both d-iterations) issued up-front
//  - branchless masking for the it=1 tail lanes (fmaf with 0/1 mask)
// Evidence: R11 A/B showed +32 ds_read/wave = +31us -> ~300cy exposed
// latency per LDS read at 2 waves/SIMD residency. Hide it under compute.
// ---------------------------------------------------------------------------
__global__ __launch_bounds__(256) void rotate_score(
    const float* __restrict__ eemb,
    const __half* __restrict__ rot,      // nullptr -> compute in-kernel
    const int* __restrict__ all_h, const int* __restrict__ all_r,
    const float* __restrict__ remb,
    float* __restrict__ out)
{
    __shared__ __half lrot[ROT_HALFS];   // 32000 bytes

    const int tid = threadIdx.x;

    if (rot != nullptr) {
        const float4* src = (const float4*)rot;
        float4* dst = (float4*)lrot;
        for (int i = tid; i < ROT_HALFS / 8; i += 256) dst[i] = src[i];
    } else {
        for (int i = tid; i < B_SIZE * EMB_DIM; i += 256) {
            int b = i / EMB_DIM;
            int d = i - b * EMB_DIM;
            int h = all_h[b];
            int r = all_r[b];
            float re_h = eemb[h * TWO_D + d];
            float im_h = eemb[h * TWO_D + EMB_DIM + d];
            float ph = remb[r * EMB_DIM + d] * PHASE_SCALE;
            float s, c;
            sincosf(ph, &s, &c);
            int base = ((b * D4 + (d >> 2)) << 3) + (d & 3);
            lrot[base]     = __float2half(re_h * c - im_h * s);
            lrot[base + 4] = __float2half(re_h * s + im_h * c);
        }
    }
    __syncthreads();

    const int lane = tid & 63;
    const int wave = tid >> 6;
    const int e0 = blockIdx.x * 16 + wave * 4;

    int e[4];
#pragma unroll
    for (int k = 0; k < 4; ++k) {
        int ek = e0 + k;
        e[k] = (ek < NUM_ENTITIES) ? ek : (NUM_ENTITIES - 1);
    }

    // d4 for the two iterations; it=0 (d4=lane) is always valid.
    const int d4a = lane;
    const int d4b_raw = 64 + lane;
    const bool vB = (d4b_raw < D4);
    const int d4b = vB ? d4b_raw : (D4 - 1);
    const float maskB = vB ? 1.0f : 0.0f;

    const float4* lrot4 = (const float4*)lrot;
    const float4* ee4 = (const float4*)eemb;

    // Issue ALL entity loads up-front: it=1's latency hides under it=0's
    // whole b-loop (~5k cycles of compute).
    float4 treA[4], timA[4], treB[4], timB[4];
#pragma unroll
    for (int k = 0; k < 4; ++k) {
        const int rb = e[k] * ROW_F4;
        treA[k] = ee4[rb + d4a];
        timA[k] = ee4[rb + D4 + d4a];
        treB[k] = ee4[rb + d4b];
        timB[k] = ee4[rb + D4 + d4b];
    }

    float v[64];                         // acc[k][b]: idx = k*16+b
#pragma unroll
    for (int i = 0; i < 64; ++i) v[i] = 0.0f;

    // ---- it = 0 (all lanes valid, plain add) with b+1 rot prefetch ----
    {
        float4 rc = lrot4[d4a];          // b = 0
#pragma unroll
        for (int b = 0; b < 16; ++b) {
            float4 rn = (b < 15) ? lrot4[(b + 1) * D4 + d4a] : rc;  // prefetch
            __half2 p0 = __builtin_bit_cast(__half2, rc.x);
            __half2 p1 = __builtin_bit_cast(__half2, rc.y);
            __half2 p2 = __builtin_bit_cast(__half2, rc.z);
            __half2 p3 = __builtin_bit_cast(__half2, rc.w);
            float rre0 = __low2float(p0), rre1 = __high2float(p0);
            float rre2 = __low2float(p1), rre3 = __high2float(p1);
            float rim0 = __low2float(p2), rim1 = __high2float(p2);
            float rim2 = __low2float(p3), rim3 = __high2float(p3);
#pragma unroll
            for (int k = 0; k < 4; ++k) {
                float dre, dim;
                dre = rre0 - treA[k].x; dim = rim0 - timA[k].x;
                v[k * 16 + b] += __builtin_amdgcn_sqrtf(dre * dre + dim * dim);
                dre = rre1 - treA[k].y; dim = rim1 - timA[k].y;
                v[k * 16 + b] += __builtin_amdgcn_sqrtf(dre * dre + dim * dim);
                dre = rre2 - treA[k].z; dim = rim2 - timA[k].z;
                v[k * 16 + b] += __builtin_amdgcn_sqrtf(dre * dre + dim * dim);
                dre = rre3 - treA[k].w; dim = rim3 - timA[k].w;
                v[k * 16 + b] += __builtin_amdgcn_sqrtf(dre * dre + dim * dim);
            }
            rc = rn;
        }
    }

    // ---- it = 1 (tail lanes masked branchlessly) with prefetch ----
    {
        float4 rc = lrot4[d4b];          // b = 0
#pragma unroll
        for (int b = 0; b < 16; ++b) {
            float4 rn = (b < 15) ? lrot4[(b + 1) * D4 + d4b] : rc;  // prefetch
            __half2 p0 = __builtin_bit_cast(__half2, rc.x);
            __half2 p1 = __builtin_bit_cast(__half2, rc.y);
            __half2 p2 = __builtin_bit_cast(__half2, rc.z);
            __half2 p3 = __builtin_bit_cast(__half2, rc.w);
            float rre0 = __low2float(p0), rre1 = __high2float(p0);
            float rre2 = __low2float(p1), rre3 = __high2float(p1);
            float rim0 = __low2float(p2), rim1 = __high2float(p2);
            float rim2 = __low2float(p3), rim3 = __high2float(p3);
#pragma unroll
            for (int k = 0; k < 4; ++k) {
                float dre, dim;
                dre = rre0 - treB[k].x; dim = rim0 - timB[k].x;
                v[k * 16 + b] = fmaf(maskB,
                    __builtin_amdgcn_sqrtf(dre * dre + dim * dim), v[k * 16 + b]);
                dre = rre1 - treB[k].y; dim = rim1 - timB[k].y;
                v[k * 16 + b] = fmaf(maskB,
                    __builtin_amdgcn_sqrtf(dre * dre + dim * dim), v[k * 16 + b]);
                dre = rre2 - treB[k].z; dim = rim2 - timB[k].z;
                v[k * 16 + b] = fmaf(maskB,
                    __builtin_amdgcn_sqrtf(dre * dre + dim * dim), v[k * 16 + b]);
                dre = rre3 - treB[k].w; dim = rim3 - timB[k].w;
                v[k * 16 + b] = fmaf(maskB,
                    __builtin_amdgcn_sqrtf(dre * dre + dim * dim), v[k * 16 + b]);
            }
            rc = rn;
        }
    }

    // Halving butterfly: lane L ends holding the full 64-lane sum of v[L].
#pragma unroll
    for (int m = 32; m >= 1; m >>= 1) {
        const bool hi = (lane & m) != 0;
#pragma unroll
        for (int i = 0; i < m; ++i) {
            float give = hi ? v[i] : v[m + i];
            float keep = hi ? v[m + i] : v[i];
            v[i] = keep + __shfl_xor(give, m, 64);
        }
    }

    const int kk = lane >> 4;            // 0..3
    const int bb = lane & 15;            // 0..15
    const int ee = e0 + kk;
    if (ee < NUM_ENTITIES) out[bb * NUM_ENTITIES + ee] = GAMMA_F - v[0];
}

extern "C" void kernel_launch(void* const* d_in, const int* in_sizes, int n_in,
                              void* d_out, int out_size, void* d_ws, size_t ws_size,
                              hipStream_t stream) {
    const int*   all_h = (const int*)d_in[0];
    const int*   all_r = (const int*)d_in[1];
    const float* eemb  = (const float*)d_in[2];
    const float* remb  = (const float*)d_in[3];
    float* out = (float*)d_out;

    __half* rot = nullptr;
    const size_t rot_bytes = (size_t)ROT_HALFS * sizeof(__half);
    if (ws_size >= rot_bytes) {
        rot = (__half*)d_ws;
        rot_precompute<<<(B_SIZE * EMB_DIM + 255) / 256, 256, 0, stream>>>(
            all_h, all_r, eemb, remb, rot);
    }

    int nblocks = (NUM_ENTITIES + 15) / 16;  // 909
    rotate_score<<<nblocks, 256, 0, stream>>>(eemb, rot, all_h, all_r, remb, out);
}

// Round 14
// 40.001 us; speedup vs baseline: 2.4173x; 1.0462x over previous
//
#include <hip/hip_runtime.h>
#include <hip/hip_fp16.h>
#include <math.h>

#define EMB_DIM 500
#define TWO_D 1000
#define D4 125                 // float4 groups per half-row (500/4)
#define ROW_F4 250             // float4 per entity row (1000/4)
#define NUM_ENTITIES 14541
#define B_SIZE 16
#define GAMMA_F 12.0f
// PI / ((GAMMA + 2) / EMB_DIM) = pi / 0.028
#define PHASE_SCALE 112.19973762820692f
#define ROT_HALFS (B_SIZE * D4 * 8)   // 16000 halfs = 32000 B

// ---------------------------------------------------------------------------
// Kernel 1: precompute rotated head embeddings as fp16, interleaved layout
// rot[b][d4][0..3] = re(4*d4 .. 4*d4+3), rot[b][d4][4..7] = im(...)
// ---------------------------------------------------------------------------
__global__ __launch_bounds__(256) void rot_precompute(
    const int* __restrict__ all_h, const int* __restrict__ all_r,
    const float* __restrict__ eemb, const float* __restrict__ remb,
    __half* __restrict__ rot)
{
    int i = blockIdx.x * 256 + threadIdx.x;
    if (i >= B_SIZE * EMB_DIM) return;
    int b = i / EMB_DIM;
    int d = i - b * EMB_DIM;
    int h = all_h[b];
    int r = all_r[b];
    float re_h = eemb[h * TWO_D + d];
    float im_h = eemb[h * TWO_D + EMB_DIM + d];
    float ph = remb[r * EMB_DIM + d] * PHASE_SCALE;
    float s, c;
    sincosf(ph, &s, &c);
    int base = ((b * D4 + (d >> 2)) << 3) + (d & 3);
    rot[base]     = __float2half(re_h * c - im_h * s);  // re_rot
    rot[base + 4] = __float2half(re_h * s + im_h * c);  // im_rot
}

// ---------------------------------------------------------------------------
// Kernel 2: R9 shape (909 blocks, 4 ents/wave, 16 evals/ds_read — the
// measured optimum) but the inner loop is PACKED FP16 (v_pk_* / 2-wide):
//   - rot stays packed (bit-select half2 from the ds_read dwords; the 256
//     cvt-to-f32 unpacks per wave are GONE)
//   - entity f32 float4 -> half2 pairs once per wave (32 cvt, amortized
//     over 16 b)
//   - diff/sq: __hsub2/__hmul2/__hfma2; sqrt: h2sqrt; acc: __hadd2
//   => per-(b,k) inner insts 24 -> 14 (~1.9x fewer)
// Precision: per-lane fp16 acc sums <=4 values (<=30 mag, ulp .016); the
// 500-wide reduction stays f32 (butterfly). New error ~0.06 abs vs 19.28
// threshold (absmax 4.0 has been constant since the all-f32 R1).
// Evidence trail: R9=39us, R13 pipelining neutral (41.8) -> plateau is
// instruction-count-bound, not scheduling-bound.
// ---------------------------------------------------------------------------
__global__ __launch_bounds__(256) void rotate_score(
    const float* __restrict__ eemb,
    const __half* __restrict__ rot,      // nullptr -> compute in-kernel
    const int* __restrict__ all_h, const int* __restrict__ all_r,
    const float* __restrict__ remb,
    float* __restrict__ out)
{
    __shared__ __half lrot[ROT_HALFS];   // 32000 bytes

    const int tid = threadIdx.x;

    if (rot != nullptr) {
        const float4* src = (const float4*)rot;
        float4* dst = (float4*)lrot;
        for (int i = tid; i < ROT_HALFS / 8; i += 256) dst[i] = src[i];
    } else {
        for (int i = tid; i < B_SIZE * EMB_DIM; i += 256) {
            int b = i / EMB_DIM;
            int d = i - b * EMB_DIM;
            int h = all_h[b];
            int r = all_r[b];
            float re_h = eemb[h * TWO_D + d];
            float im_h = eemb[h * TWO_D + EMB_DIM + d];
            float ph = remb[r * EMB_DIM + d] * PHASE_SCALE;
            float s, c;
            sincosf(ph, &s, &c);
            int base = ((b * D4 + (d >> 2)) << 3) + (d & 3);
            lrot[base]     = __float2half(re_h * c - im_h * s);
            lrot[base + 4] = __float2half(re_h * s + im_h * c);
        }
    }
    __syncthreads();

    const int lane = tid & 63;
    const int wave = tid >> 6;
    const int e0 = blockIdx.x * 16 + wave * 4;

    int e[4];
#pragma unroll
    for (int k = 0; k < 4; ++k) {
        int ek = e0 + k;
        e[k] = (ek < NUM_ENTITIES) ? ek : (NUM_ENTITIES - 1);
    }

    __half2 acc[64];                     // acc[k][b]: idx = k*16+b, 2 partials
#pragma unroll
    for (int i = 0; i < 64; ++i) acc[i] = __float2half2_rn(0.0f);

    const float4* lrot4 = (const float4*)lrot;
    const float4* ee4 = (const float4*)eemb;

#pragma unroll
    for (int it = 0; it < 2; ++it) {
        const int d4 = it * 64 + lane;
        if (d4 < D4) {
            // Entity rows: load f32, convert once to packed half2 (amortized
            // over the 16-b loop below).
            __half2 te01[4], te23[4], ti01[4], ti23[4];
#pragma unroll
            for (int k = 0; k < 4; ++k) {
                const int rb = e[k] * ROW_F4;
                float4 tre = ee4[rb + d4];
                float4 tim = ee4[rb + D4 + d4];
                te01[k] = __floats2half2_rn(tre.x, tre.y);
                te23[k] = __floats2half2_rn(tre.z, tre.w);
                ti01[k] = __floats2half2_rn(tim.x, tim.y);
                ti23[k] = __floats2half2_rn(tim.z, tim.w);
            }
#pragma unroll
            for (int b = 0; b < 16; ++b) {
                float4 rv = lrot4[b * D4 + d4];
                __half2 re01 = __builtin_bit_cast(__half2, rv.x);
                __half2 re23 = __builtin_bit_cast(__half2, rv.y);
                __half2 im01 = __builtin_bit_cast(__half2, rv.z);
                __half2 im23 = __builtin_bit_cast(__half2, rv.w);
#pragma unroll
                for (int k = 0; k < 4; ++k) {
                    __half2 dre = __hsub2(re01, te01[k]);
                    __half2 dim = __hsub2(im01, ti01[k]);
                    __half2 r0 = h2sqrt(__hfma2(dim, dim, __hmul2(dre, dre)));
                    dre = __hsub2(re23, te23[k]);
                    dim = __hsub2(im23, ti23[k]);
                    __half2 r1 = h2sqrt(__hfma2(dim, dim, __hmul2(dre, dre)));
                    acc[k * 16 + b] = __hadd2(acc[k * 16 + b], __hadd2(r0, r1));
                }
            }
        }
    }

    // Convert packed partials to f32 (hi+lo) BEFORE the wide reduction —
    // the 500-elem summation stays in f32.
    float v[64];
#pragma unroll
    for (int i = 0; i < 64; ++i)
        v[i] = __low2float(acc[i]) + __high2float(acc[i]);

    // Halving butterfly: lane L ends holding the full 64-lane sum of v[L].
#pragma unroll
    for (int m = 32; m >= 1; m >>= 1) {
        const bool hi = (lane & m) != 0;
#pragma unroll
        for (int i = 0; i < m; ++i) {
            float give = hi ? v[i] : v[m + i];
            float keep = hi ? v[m + i] : v[i];
            v[i] = keep + __shfl_xor(give, m, 64);
        }
    }

    const int kk = lane >> 4;            // 0..3
    const int bb = lane & 15;            // 0..15
    const int ee = e0 + kk;
    if (ee < NUM_ENTITIES) out[bb * NUM_ENTITIES + ee] = GAMMA_F - v[0];
}

extern "C" void kernel_launch(void* const* d_in, const int* in_sizes, int n_in,
                              void* d_out, int out_size, void* d_ws, size_t ws_size,
                              hipStream_t stream) {
    const int*   all_h = (const int*)d_in[0];
    const int*   all_r = (const int*)d_in[1];
    const float* eemb  = (const float*)d_in[2];
    const float* remb  = (const float*)d_in[3];
    float* out = (float*)d_out;

    __half* rot = nullptr;
    const size_t rot_bytes = (size_t)ROT_HALFS * sizeof(__half);
    if (ws_size >= rot_bytes) {
        rot = (__half*)d_ws;
        rot_precompute<<<(B_SIZE * EMB_DIM + 255) / 256, 256, 0, stream>>>(
            all_h, all_r, eemb, remb, rot);
    }

    int nblocks = (NUM_ENTITIES + 15) / 16;  // 909
    rotate_score<<<nblocks, 256, 0, stream>>>(eemb, rot, all_h, all_r, remb, out);
}